// Round 6
// baseline (376.521 us; speedup 1.0000x reference)
//
#include <hip/hip_runtime.h>
#include <hip/hip_bf16.h>
#include <stdint.h>

// DecoderSelfAttention: B=8, S=2048, D=1024 (d_k=d_v=d_model)
// Round 6: mm_core rebuilt around v_mfma_f32_32x32x16_bf16 with 128x64
// per-wave tiles (256x128 block tile, BK=64). LDS-read bytes/FLOP -25%,
// MFMA issue cycles/FLOP -17% vs the 16x16/64x64 core. acc 4x2 floatx16.
// Swapped operands mfma(bfr, af): our-M = lane&31 (= A-frag row),
// our-N = 8*(reg>>2) + 4*(lane>>5) + (reg&3) -> packed epilogue stores.
// XOR-swizzled LDS placement (unit = row*8 + (cc ^ (row&7))), conflict-free.
// Pipeline: prep ; qkproj ; vproj ; qk_p (exp, no-max softmax) ; pv (*1/l).

typedef __bf16 bf16_t;
typedef __bf16 bf16x4 __attribute__((ext_vector_type(4)));
typedef __bf16 bf16x8 __attribute__((ext_vector_type(8)));
typedef float  floatx4  __attribute__((ext_vector_type(4)));
typedef float  floatx16 __attribute__((ext_vector_type(16)));

#define NB 8
#define SS 2048
#define DD 1024
#define INV_SCALE 0.03125f   // 1/sqrt(1024)

__device__ __forceinline__ void async_ld16(const void* g, void* l) {
  __builtin_amdgcn_global_load_lds(
      (const __attribute__((address_space(1))) void*)g,
      (__attribute__((address_space(3))) void*)l, 16, 0, 0);
}

// 256x128 tile GEMM core, C = A * B^T, A[M,K] row-major (256 rows),
// B[N,K] row-major (128 rows), bf16, BK=64, 256 threads = 4 waves (2x2),
// each wave 128x64 out as 4x2 of 32x32x16 MFMA. kTiles = K/64 steps.
// sA = 256*64 bf16 (32KB), sB = 128*64 bf16 (16KB).
__device__ __forceinline__ void mm_core(const bf16_t* __restrict__ Ab,
                                        const bf16_t* __restrict__ Bb,
                                        int lda, int ldb, int kTiles,
                                        bf16_t* sA, bf16_t* sB,
                                        floatx16 acc[4][2]) {
  const int t    = threadIdx.x;
  const int lane = t & 63;
  const int wm   = (t >> 6) >> 1;   // 0..1: wave row (128 M-rows each)
  const int wn   = (t >> 6) & 1;    // 0..1: wave col (64 N-cols each)
  const int fm   = lane & 31;       // row within a 32-frag
  const int half = lane >> 5;       // 0..1: K-half of the frag
  const int xo   = fm & 7;          // per-lane XOR swizzle key

  // staging: A 2048 16B-units (8/thread), B 1024 units (4/thread)
  const bf16_t* ga[8]; bf16_t* la[8];
  const bf16_t* gb[4]; bf16_t* lb[4];
#pragma unroll
  for (int k = 0; k < 8; ++k) {
    const int u = k * 256 + t, row = u >> 3, cc = (u & 7) ^ (row & 7);
    ga[k] = Ab + (size_t)row * lda + cc * 8;
    la[k] = sA + u * 8;
  }
#pragma unroll
  for (int k = 0; k < 4; ++k) {
    const int u = k * 256 + t, row = u >> 3, cc = (u & 7) ^ (row & 7);
    gb[k] = Bb + (size_t)row * ldb + cc * 8;
    lb[k] = sB + u * 8;
  }

  const bf16_t* pa = sA + (size_t)(wm * 128 + fm) * 64;   // + i*2048 + co
  const bf16_t* pb = sB + (size_t)(wn * 64 + fm) * 64;    // + j*2048 + co

  for (int kt = 0; kt < kTiles; ++kt) {
    const int ko = kt * 64;
#pragma unroll
    for (int k = 0; k < 8; ++k) async_ld16(ga[k] + ko, la[k]);
#pragma unroll
    for (int k = 0; k < 4; ++k) async_ld16(gb[k] + ko, lb[k]);
    __syncthreads();   // drains vmcnt(0): LDS tiles complete
#pragma unroll
    for (int s = 0; s < 4; ++s) {            // 4 K-steps of 16
      const int co = (((2 * s + half)) ^ xo) * 8;
      bf16x8 af[4], bfr[2];
#pragma unroll
      for (int i = 0; i < 4; ++i) af[i]  = *(const bf16x8*)(pa + i * 2048 + co);
#pragma unroll
      for (int j = 0; j < 2; ++j) bfr[j] = *(const bf16x8*)(pb + j * 2048 + co);
#pragma unroll
      for (int i = 0; i < 4; ++i)
#pragma unroll
        for (int j = 0; j < 2; ++j)
          acc[i][j] = __builtin_amdgcn_mfma_f32_32x32x16_bf16(bfr[j], af[i], acc[i][j], 0, 0, 0);
    }
    __syncthreads();   // all reads done before next staging overwrites
  }
}

__device__ __forceinline__ void zero_acc(floatx16 acc[4][2]) {
#pragma unroll
  for (int i = 0; i < 4; ++i)
#pragma unroll
    for (int j = 0; j < 2; ++j)
#pragma unroll
      for (int r = 0; r < 16; ++r) acc[i][j][r] = 0.f;
}

// ---------------- fused converters: x->bf16 and W->W^T bf16 ----------------

__global__ __launch_bounds__(256) void prep(const float* __restrict__ x,
                                            const float* __restrict__ Wq,
                                            const float* __restrict__ Wk,
                                            const float* __restrict__ Wv,
                                            bf16_t* __restrict__ xb,
                                            bf16_t* __restrict__ Wt) {
  __shared__ float tile[32][33];
  const int bid = blockIdx.x;
  const int t = threadIdx.x;
  if (bid < 16384) {
    size_t i = (size_t)bid * 256 + t;
    float4 v = ((const float4*)x)[i];
    bf16x4 o = {(bf16_t)v.x, (bf16_t)v.y, (bf16_t)v.z, (bf16_t)v.w};
    ((bf16x4*)xb)[i] = o;
  } else {
    const int wb = bid - 16384;
    const int z = wb >> 10;                 // 0,1,2 -> Wq,Wk,Wv
    const int rem = wb & 1023;
    const float* W = (z == 0) ? Wq : (z == 1 ? Wk : Wv);
    bf16_t* O = Wt + (size_t)z * DD * DD;
    const int ty = t >> 3;
    const int tx = t & 7;
    const int k0 = (rem >> 5) * 32, n0 = (rem & 31) * 32;
    float4 v = *(const float4*)(W + (size_t)(k0 + ty) * DD + n0 + tx * 4);
    tile[ty][tx * 4 + 0] = v.x;
    tile[ty][tx * 4 + 1] = v.y;
    tile[ty][tx * 4 + 2] = v.z;
    tile[ty][tx * 4 + 3] = v.w;
    __syncthreads();
    bf16x4 o = {(bf16_t)tile[tx * 4 + 0][ty], (bf16_t)tile[tx * 4 + 1][ty],
                (bf16_t)tile[tx * 4 + 2][ty], (bf16_t)tile[tx * 4 + 3][ty]};
    *(bf16x4*)(O + (size_t)(n0 + ty) * DD + k0 + tx * 4) = o;
  }
}

// ---------------- shared bf16 epilogue (M=lane&31 row, packed 8B stores) ----------------

__device__ __forceinline__ void store_c_bf16(floatx16 acc[4][2], bf16_t* Cb, int ldc) {
  const int lane = threadIdx.x & 63;
  const int wm = (threadIdx.x >> 6) >> 1, wn = (threadIdx.x >> 6) & 1;
  const int m0 = wm * 128 + (lane & 31);
  const int n0 = wn * 64 + (lane >> 5) * 4;
#pragma unroll
  for (int i = 0; i < 4; ++i) {
    bf16_t* crow = Cb + (size_t)(m0 + i * 32) * ldc;
#pragma unroll
    for (int j = 0; j < 2; ++j)
#pragma unroll
      for (int g = 0; g < 4; ++g) {
        bf16x4 o = {(bf16_t)acc[i][j][4 * g + 0], (bf16_t)acc[i][j][4 * g + 1],
                    (bf16_t)acc[i][j][4 * g + 2], (bf16_t)acc[i][j][4 * g + 3]};
        *(bf16x4*)(crow + n0 + j * 32 + g * 8) = o;
      }
  }
}

// ---------------- QK projection: [Q|K] = x @ [Wq|Wk] ----------------
// grid dim3(64,16): mt fastest -> XCD = mt&7, 8 A-panels (4MB) resident/XCD.

__global__ __launch_bounds__(256, 2) void qkproj_gemm(
    const bf16_t* __restrict__ xb, const bf16_t* __restrict__ Wt,
    bf16_t* __restrict__ QKb) {
  __shared__ __attribute__((aligned(16))) bf16_t sA[256 * 64];
  __shared__ __attribute__((aligned(16))) bf16_t sB[128 * 64];
  const int mt = blockIdx.x, nt = blockIdx.y;
  floatx16 acc[4][2];
  zero_acc(acc);
  mm_core(xb + (size_t)mt * 256 * DD, Wt + (size_t)nt * 128 * DD,
          DD, DD, DD / 64, sA, sB, acc);
  store_c_bf16(acc, QKb + (size_t)mt * 256 * (2 * DD) + nt * 128, 2 * DD);
}

// ---------------- V projection: V^T[b] = Wv^T @ x[b]^T ----------------
// 1D grid 512: nb = bid&127 fastest (XCD = n&7 keeps xb panels resident).

__global__ __launch_bounds__(256, 2) void vproj_gemm(
    const bf16_t* __restrict__ xb, const bf16_t* __restrict__ Wt,
    bf16_t* __restrict__ VtB) {
  __shared__ __attribute__((aligned(16))) bf16_t sA[256 * 64];
  __shared__ __attribute__((aligned(16))) bf16_t sB[128 * 64];
  const int bid = blockIdx.x;
  const int nb = bid & 127;
  const int m  = bid >> 7;          // 0..3 (dv 256-tile)
  const int n  = nb & 15;           // seq 128-tile
  const int b  = nb >> 4;           // batch
  floatx16 acc[4][2];
  zero_acc(acc);
  mm_core(Wt + (size_t)2 * DD * DD + (size_t)m * 256 * DD,
          xb + (size_t)b * SS * DD + (size_t)n * 128 * DD,
          DD, DD, DD / 64, sA, sB, acc);
  store_c_bf16(acc, VtB + (size_t)b * DD * SS + (size_t)m * 256 * SS + n * 128, SS);
}

// ---------------- QK^T -> P' = exp(s) bf16 (causal tiles) + row-sum partials ----------------
// q-tiles of 256 rows (qi 0..7), kv-tiles of 128 (ki 0..2qi+1): 72 tiles/batch.
// grid 576: b = bid&7 (XCD==batch), tt = bid>>3.

__global__ __launch_bounds__(256, 2) void qk_p(
    const bf16_t* __restrict__ Q, const bf16_t* __restrict__ K,
    bf16_t* __restrict__ P, float* __restrict__ lpart) {
  const int b  = blockIdx.x & 7;
  const int tt = blockIdx.x >> 3;       // 0..71
  int qi = (int)((sqrtf(4.0f * tt + 1.0f) - 1.0f) * 0.5f);
  while ((qi + 1) * (qi + 2) <= tt) ++qi;
  while (qi * (qi + 1) > tt) --qi;
  const int ki = tt - qi * (qi + 1);    // 0..2qi+1

  __shared__ __attribute__((aligned(16))) bf16_t sA[256 * 64];
  __shared__ __attribute__((aligned(16))) bf16_t sB[128 * 64];
  __shared__ float reds[2][256];
  floatx16 acc[4][2];
  zero_acc(acc);
  mm_core(Q + ((size_t)b * SS + qi * 256) * (2 * DD),
          K + ((size_t)b * SS + ki * 128) * (2 * DD),
          2 * DD, 2 * DD, DD / 64, sA, sB, acc);

  const int lane = threadIdx.x & 63;
  const int wm = (threadIdx.x >> 6) >> 1, wn = (threadIdx.x >> 6) & 1;
  const int m0 = wm * 128 + (lane & 31);
  const int n0 = wn * 64 + (lane >> 5) * 4;
  const int diffk = ki * 128 - qi * 256;   // mask iff (n + diffk) > m ; <0 => never
  bf16_t* Pb = P + (size_t)b * SS * SS;

#pragma unroll
  for (int i = 0; i < 4; ++i) {
    const int m = m0 + i * 32;
    float partial = 0.f;
    bf16_t* prow = Pb + (size_t)(qi * 256 + m) * SS + ki * 128;
#pragma unroll
    for (int j = 0; j < 2; ++j)
#pragma unroll
      for (int g = 0; g < 4; ++g) {
        const int nb0 = n0 + j * 32 + g * 8;
        floatx4 p;
#pragma unroll
        for (int r = 0; r < 4; ++r) {
          const float s = acc[i][j][4 * g + r] * INV_SCALE;
          p[r] = ((nb0 + r + diffk) > m) ? 0.f : __expf(s);
          partial += p[r];
        }
        bf16x4 o = {(bf16_t)p[0], (bf16_t)p[1], (bf16_t)p[2], (bf16_t)p[3]};
        *(bf16x4*)(prow + nb0) = o;
      }
    partial += __shfl_xor(partial, 32);   // combine K-halves (same row)
    if (lane < 32) reds[wn][m] = partial;
  }
  __syncthreads();
  const int t = threadIdx.x;
  {
    size_t row = (size_t)b * SS + qi * 256 + t;
    lpart[row * 16 + ki] = reds[0][t] + reds[1][t];
  }
}

// ---------------- PV GEMM: out = (P' @ V) * 1/rowsum, causal-truncated K ----------------
// 512 blocks: g = bid>>6, qi = g<4 ? 7-g : g-4 (pairs sum work to 9 per CU),
// sub = bid&63: nj = sub>>3, b = sub&7 (XCD==batch).

__global__ __launch_bounds__(256, 2) void pv_gemm(
    const bf16_t* __restrict__ P, const bf16_t* __restrict__ Vt,
    const float* __restrict__ lpart, float* __restrict__ Out) {
  const int bid = blockIdx.x;
  const int g  = bid >> 6;
  const int qi = (g < 4) ? (7 - g) : (g - 4);
  const int nj = (bid >> 3) & 7;
  const int b  = bid & 7;

  __shared__ __attribute__((aligned(16))) bf16_t sA[256 * 64];
  __shared__ __attribute__((aligned(16))) bf16_t sB[128 * 64];
  __shared__ float sRl[256];
  const int t = threadIdx.x;
  {
    const float* lp = lpart + ((size_t)b * SS + qi * 256 + t) * 16;
    float L = 0.f;
    const int nch = 2 * qi + 2;
    for (int ci = 0; ci < nch; ++ci) L += lp[ci];
    sRl[t] = 1.0f / L;
  }
  floatx16 acc[4][2];
  zero_acc(acc);
  mm_core(P + (size_t)b * SS * SS + (size_t)qi * 256 * SS,
          Vt + (size_t)b * DD * SS + (size_t)nj * 128 * SS,
          SS, SS, (qi + 1) * 4, sA, sB, acc);   // K = (qi+1)*256

  const int lane = threadIdx.x & 63;
  const int wm = (threadIdx.x >> 6) >> 1, wn = (threadIdx.x >> 6) & 1;
  const int m0 = wm * 128 + (lane & 31);
  const int n0 = wn * 64 + (lane >> 5) * 4;
  float* Cb = Out + (size_t)b * SS * DD + (size_t)qi * 256 * DD + nj * 128;
#pragma unroll
  for (int i = 0; i < 4; ++i) {
    const int m = m0 + i * 32;
    const float scale = sRl[m];
    float* crow = Cb + (size_t)m * DD;
#pragma unroll
    for (int j = 0; j < 2; ++j)
#pragma unroll
      for (int g2 = 0; g2 < 4; ++g2) {
        floatx4 o;
#pragma unroll
        for (int r = 0; r < 4; ++r) o[r] = acc[i][j][4 * g2 + r] * scale;
        *(floatx4*)(crow + n0 + j * 32 + g2 * 8) = o;
      }
  }
}

// ---------------- launch ----------------

extern "C" void kernel_launch(void* const* d_in, const int* in_sizes, int n_in,
                              void* d_out, int out_size, void* d_ws, size_t ws_size,
                              hipStream_t stream) {
  const float* x  = (const float*)d_in[0];
  const float* Wq = (const float*)d_in[1];
  const float* Wk = (const float*)d_in[2];
  const float* Wv = (const float*)d_in[3];
  float* out = (float*)d_out;

  char* ws = (char*)d_ws;
  // workspace layout (bytes)
  bf16_t* xb   = (bf16_t*)(ws);                      // 33,554,432  x bf16 [B*S, D]
  bf16_t* Wt   = (bf16_t*)(ws + 33554432ull);        //  6,291,456  Wq^T,Wk^T,Wv^T bf16 [N,K]
  bf16_t* QKb  = (bf16_t*)(ws + 39845888ull);        // 67,108,864  [Q|K] bf16 [B*S, 2048]
  bf16_t* VtB  = (bf16_t*)(ws + 106954752ull);       // 33,554,432  V^T bf16 [B, D, S]
  bf16_t* Pb   = (bf16_t*)(ws + 140509184ull);       // 67,108,864  P' bf16 [B, S, S]
  float*  lpart= (float*)(ws + 207618048ull);        //  1,048,576  row-sum partials [B*S,16]
  (void)in_sizes; (void)n_in; (void)out_size; (void)ws_size;

  // 1. convert x + convert/transpose weights
  prep<<<16384 + 3072, 256, 0, stream>>>(x, Wq, Wk, Wv, xb, Wt);
  // 2. [Q|K] = x @ [Wq|Wk]  (M=16384, N=2048, K=1024), 256x128 tiles, mt-fastest
  qkproj_gemm<<<dim3(64, 16), 256, 0, stream>>>(xb, Wt, QKb);
  // 3. V^T = Wv^T @ x^T, 256x128 tiles, nb-fastest
  vproj_gemm<<<512, 256, 0, stream>>>(xb, Wt, VtB);
  // 4. P' = exp(QK^T/32) on causal 256x128 tiles + row-sum partials, XCD==batch
  qk_p<<<576, 256, 0, stream>>>(QKb, QKb + DD, Pb, lpart);
  // 5. out = (P' @ V) * (1/rowsum), work-paired qi ordering, XCD==batch
  pv_gemm<<<512, 256, 0, stream>>>(Pb, VtB, lpart, out);
}